// Round 12
// baseline (8400.665 us; speedup 1.0000x reference)
//
#include <hip/hip_runtime.h>
#include <hip/hip_bf16.h>

// Problem: B=32, T=128, I=H=O=512, L=2, bidirectional GRU + FC head.
// ws layout (bytes):
//   proj (bf16): [2][128][32][1536]            = 12,582,912 elems * 2B = 25.17 MB
//   seq  (fp32): [2][128][32][512]             =  4,194,304 elems * 4B = 16.78 MB
//   slabs(fp32): [2l][2d][128jb][6144]         =  6,291,456 elems * 4B = 25.17 MB
// total 67.12 MB; sync slots live in __device__ globals (zeroed by repack each launch)
#define PROJ_ELEMS 12582912
#define SEQ_ELEMS  4194304
#define SLAB_PER_BLK 6144

typedef float f32x4 __attribute__((ext_vector_type(4)));

// Block-granular dataflow slots (R7-proven): g_slots[ld*128 + jb] = epoch published
// by block (d,jb) of layer ld: value t+1 means h(t) cols [4jb,4jb+4) are LLC-visible.
// All traffic RELAXED agent-scope (sc1) — no wbl2/inv. Monotonic, no reset.
__device__ unsigned g_slots[512];

// ---------------- proj GEMM: [8192 x 1536] = src @ [Wxh | Wxr] + bias -> bf16 ----------------
// grid (12, 64), block 256. 128x128 tile, 8x8 per-thread register tile.
__global__ __launch_bounds__(256)
void proj_kernel(const float* __restrict__ src,
                 const float* __restrict__ Wxh, const float* __restrict__ bxh,
                 const float* __restrict__ Wxr, const float* __restrict__ bxr,
                 __hip_bfloat16* __restrict__ proj, int layer)
{
    __shared__ float As[32][137];   // [k][row] transposed A tile
    __shared__ float Ws[32][132];   // [k][col]
    const int tid  = threadIdx.x;
    const int col0 = blockIdx.x * 128;
    const int row0 = blockIdx.y * 128;
    const int d    = row0 >> 12;              // rows 0..4095 = dir0, 4096..8191 = dir1
    const int ld   = layer * 2 + d;
    const int tx = tid & 15, ty = tid >> 4;

    const bool is_xr = (col0 >= 1024);
    const float* Wbase = is_xr ? (Wxr + (size_t)ld * 512 * 512 + (col0 - 1024))
                               : (Wxh + (size_t)ld * 512 * 1024 + col0);
    const int wstride = is_xr ? 512 : 1024;
    const float* bias = is_xr ? (bxr + ld * 512 + (col0 - 1024))
                              : (bxh + ld * 1024 + col0);

    float acc[8][8];
    #pragma unroll
    for (int i = 0; i < 8; i++)
        #pragma unroll
        for (int j = 0; j < 8; j++) acc[i][j] = 0.f;

    for (int k0 = 0; k0 < 512; k0 += 32) {
        #pragma unroll
        for (int v = 0; v < 4; v++) {
            int idx = tid + v * 256;
            int r   = idx >> 3;
            int c4  = (idx & 7) << 2;
            int gm  = row0 + r;
            int rr  = gm & 4095;
            int tt  = rr >> 5, bb = rr & 31;
            const float* p;
            if (layer == 0) {
                int ts = (gm >= 4096) ? (127 - tt) : tt;  // dir1 reads reversed time
                p = src + ((size_t)bb * 128 + ts) * 512 + (k0 + c4);
            } else {
                p = src + (((size_t)(gm >> 12) * 128 + tt) * 32 + bb) * 512 + (k0 + c4);
            }
            float4 vv = *(const float4*)p;
            As[c4 + 0][r] = vv.x; As[c4 + 1][r] = vv.y;
            As[c4 + 2][r] = vv.z; As[c4 + 3][r] = vv.w;
        }
        #pragma unroll
        for (int v = 0; v < 4; v++) {
            int idx = tid + v * 256;
            int kr  = idx >> 5;
            int c4  = (idx & 31) << 2;
            *(float4*)&Ws[kr][c4] = *(const float4*)(Wbase + (size_t)(k0 + kr) * wstride + c4);
        }
        __syncthreads();
        #pragma unroll
        for (int kk = 0; kk < 32; kk++) {
            float a[8], w[8];
            *(float4*)&a[0] = *(const float4*)&As[kk][ty * 8];
            *(float4*)&a[4] = *(const float4*)&As[kk][ty * 8 + 4];
            *(float4*)&w[0] = *(const float4*)&Ws[kk][tx * 8];
            *(float4*)&w[4] = *(const float4*)&Ws[kk][tx * 8 + 4];
            #pragma unroll
            for (int i = 0; i < 8; i++)
                #pragma unroll
                for (int j = 0; j < 8; j++)
                    acc[i][j] += a[i] * w[j];
        }
        __syncthreads();
    }
    #pragma unroll
    for (int i = 0; i < 8; i++) {
        int gm = row0 + ty * 8 + i;
        __hip_bfloat16* dst = proj + (size_t)gm * 1536 + col0 + tx * 8;
        #pragma unroll
        for (int j = 0; j < 8; j++)
            dst[j] = __float2bfloat16(acc[i][j] + bias[tx * 8 + j]);
    }
}

// ---------------- weight repack: per-(ld,jb) contiguous slab ----------------
// slab[(ld*128+jb)][idx], idx = (g*4+cg)*12 + e*4 + ki ; k = g*4+ki, j = jb*4+cg
// e: 0 = Whh z-col j, 1 = Whh r-col 512+j, 2 = Whr g-col j.
// Also zeroes the dataflow slots (must run before the gru kernels).
__global__ __launch_bounds__(256)
void repack_kernel(const float* __restrict__ Whh, const float* __restrict__ Whr,
                   float* __restrict__ slabs)
{
    if (blockIdx.x == 0) {
        g_slots[threadIdx.x] = 0u;
        g_slots[threadIdx.x + 256] = 0u;
    }
    const int blk = blockIdx.x;           // 0..511 = ld*128 + jb
    const int ld = blk >> 7, jb = blk & 127;
    const float* WhhL = Whh + (size_t)ld * 512 * 1024;
    const float* WhrL = Whr + (size_t)ld * 512 * 512;
    float* out = slabs + (size_t)blk * SLAB_PER_BLK;
    for (int u = 0; u < 24; u++) {
        int idx = threadIdx.x + u * 256;  // 0..6143
        int rec = idx / 12, r3 = idx % 12;
        int g = rec >> 2, cg = rec & 3;
        int e = r3 >> 2, ki = r3 & 3;
        int k = g * 4 + ki, j = jb * 4 + cg;
        float v;
        if (e == 0)      v = WhhL[(size_t)k * 1024 + j];
        else if (e == 1) v = WhhL[(size_t)k * 1024 + 512 + j];
        else             v = WhrL[(size_t)k * 512 + j];
        out[idx] = v;
    }
}

// ---------------- fused GRU sequence: all 128 timesteps, one launch ----------------
// R12 = R11 skeleton (proven) + weight-volume attack. R5-R11 invariance at
// ~1100-1300 us/layer across 4 sync/staging schemes localized the floor in the
// LDS data volume of the weight reads: every wave reads the full 16KB wz+wr set
// each step (32 distinct 16B records per instruction = 4 LDS data-cycles;
// SQ_LDS_BANK_CONFLICT 6.66e7 == this serialization, not a banking bug).
// (a) wz -> REGISTERS: loop-invariant per thread, 16 x f32x4 = 64 VGPR
//     (52+64 = 116 <= 128, 4 waves/SIMD preserved). Removes 1/3 of DS instrs
//     and their data cycles. Same values, same summation order -> same absmax.
// (b) wr re-padded in LDS at slot rec + (rec>>6): per-instr lanes spread
//     (cgi+kq) mod 8 -> exactly 4 addrs per bank-quad = the data floor
//     (old layout aliased 8-way on 4 quads).
// (c) wg stays on the L1/TA pipe (global slab).  DS ~2.5 -> ~1.2 us/step.
// Sync protocol, staging, hv_self register, poll/publish: byte-identical to R11.
__global__ __launch_bounds__(1024, 4)
void gru_seq_kernel(const __hip_bfloat16* __restrict__ proj, float* __restrict__ seq,
                    const float* __restrict__ slabs,
                    const float* __restrict__ bhh, const float* __restrict__ bhr,
                    int layer)
{
    __shared__ __align__(16) float hs[16 * 1024];  // per-wave 4KB: [w][row2][slot128*4]
    __shared__ __align__(16) float wlds[4100];     // wr only (520 f32x4 used; padded
                                                   // size keeps LDS>80KB -> 1 block/CU)
    const int tid  = threadIdx.x;
    const int d    = blockIdx.x >> 7;
    const int jb   = blockIdx.x & 127;
    const int ld   = layer * 2 + d;
    const int cgi  = tid & 3;
    const int kq   = (tid >> 2) & 7;
    const int b    = tid >> 5;
    const int w    = tid >> 6;
    const int lane = tid & 63;
    const int brl  = (tid >> 5) & 1;
    const int j    = jb * 4 + cgi;

    // loop invariants
    const f32x4* wrec = (const f32x4*)slabs + (size_t)(ld * 128 + jb) * 1536;
    const float bz = bhh[ld * 1024 + j];
    const float br = bhh[ld * 1024 + 512 + j];
    const float bg = bhr[ld * 512 + j];
    const float* hbase = seq + (size_t)(d * 128) * 32 * 512;
    const __hip_bfloat16* pbase = proj + ((size_t)(d * 128) * 32 + b) * 1536 + j;
    float* wout = seq + ((size_t)(d * 128) * 32 + b) * 512 + j;
    unsigned* slot_base = &g_slots[ld * 128];
    unsigned* s0p = slot_base + lane;    // each wave polls all 128 block slots
    unsigned* s1p = s0p + 64;
    float* hw = &hs[w * 1024];           // wave-private staging region (4KB)

    // one-time: wr -> LDS at padded slot i + (i>>6)  (i = rec; rec>>6 == kq)
    if (tid < 512) {
        int i = tid;                     // rec 0..511
        ((f32x4*)wlds)[i + (i >> 6)] = wrec[i * 3 + 1];
    }
    // one-time: wz -> registers (loop-invariant; static indexing via full unroll)
    f32x4 wzr[16];
    #pragma unroll
    for (int gg = 0; gg < 16; gg++)
        wzr[gg] = wrec[(size_t)((kq * 16 + gg) * 4 + cgi) * 3];
    __syncthreads();                     // wlds visible to all waves

    __hip_bfloat16 rz = pbase[0], rr_ = pbase[512], rg = pbase[1024];
    float hv_prev = 0.f;                 // h(t-1)[b][j] — this thread computes it

    for (int t = 0; t < 128; ++t) {
        float az = 0.f, ar = 0.f, ag = 0.f;
        if (t > 0) {
            // wait until ALL 128 producer blocks published h(t-1)  (proven R7 poll)
            const unsigned tgt = (unsigned)t;
            for (;;) {
                unsigned a = __hip_atomic_load(s0p, __ATOMIC_RELAXED,
                                               __HIP_MEMORY_SCOPE_AGENT);
                unsigned c = __hip_atomic_load(s1p, __ATOMIC_RELAXED,
                                               __HIP_MEMORY_SCOPE_AGENT);
                if (__all(a >= tgt && c >= tgt)) break;
                __builtin_amdgcn_s_sleep(1);
            }
            asm volatile("" ::: "memory");   // keep staging loads below the poll

            // stage h(t-1)[2w..2w+1][:] (4KB contiguous) into wave-private hs;
            // swizzle slot = g ^ ((g>>4)&7) -> GEMV reads are a free 2-way
            const float* hsrc = hbase + ((size_t)(t - 1) * 32 + 2 * w) * 512;
            f32x4 tmp[4];
            #pragma unroll
            for (int v = 0; v < 4; v++) {
                int id = lane + v * 64;          // f4 id 0..255 within wave tile
                asm volatile("global_load_dwordx4 %0, %1, off sc0 sc1"
                             : "=v"(tmp[v])
                             : "v"((const void*)(hsrc + (size_t)id * 4)));
            }
            asm volatile("s_waitcnt vmcnt(0)" ::: "memory");
            #pragma unroll
            for (int v = 0; v < 4; v++) {
                int id  = lane + v * 64;
                int row = id >> 7, g = id & 127;
                int sl  = g ^ ((g >> 4) & 7);
                *(f32x4*)&hw[row * 512 + (sl << 2)] = tmp[v];
            }
            // no barrier: hw is wave-private; compiler inserts lgkmcnt for RAW

            #pragma unroll
            for (int gg = 0; gg < 16; gg++) {
                int g   = kq * 16 + gg;
                int sl  = g ^ kq;                 // (g>>4)&7 == kq here
                int rec = g * 4 + cgi;
                float4 h4 = *(const float4*)&hw[brl * 512 + (sl << 2)];
                f32x4 wz = wzr[gg];                             // registers
                f32x4 wr = ((const f32x4*)wlds)[rec + kq];      // LDS, data-floor
                f32x4 wg = wrec[rec * 3 + 2];                   // global slab, L1
                az += h4.x * wz.x + h4.y * wz.y + h4.z * wz.z + h4.w * wz.w;
                ar += h4.x * wr.x + h4.y * wr.y + h4.z * wr.z + h4.w * wr.w;
                ag += h4.x * wg.x + h4.y * wg.y + h4.z * wg.z + h4.w * wg.w;
            }
            // combine the 8 k-slices (kq = lane bits 2..4)
            az += __shfl_xor(az, 4, 64);  ar += __shfl_xor(ar, 4, 64);  ag += __shfl_xor(ag, 4, 64);
            az += __shfl_xor(az, 8, 64);  ar += __shfl_xor(ar, 8, 64);  ag += __shfl_xor(ag, 8, 64);
            az += __shfl_xor(az, 16, 64); ar += __shfl_xor(ar, 16, 64); ag += __shfl_xor(ag, 16, 64);
        }

        float pz = __bfloat162float(rz);
        float pr = __bfloat162float(rr_);
        float pg = __bfloat162float(rg);
        float z  = 1.f / (1.f + __expf(-(az + pz + bz)));
        float r  = 1.f / (1.f + __expf(-(ar + pr + br)));
        float gt = tanhf((ag + bg) * r + pg);
        float hn = z * hv_prev + (1.f - z) * gt;
        hv_prev = hn;                      // becomes hv_self of step t+1
        if (kq == 0)   // coherent (sc1) write-through: LLC is the merge point
            __hip_atomic_store(wout + (size_t)t * 32 * 512, hn,
                               __ATOMIC_RELAXED, __HIP_MEMORY_SCOPE_AGENT);

        // ---- single per-step barrier + block-granular publish (proven R7) ----
        if (t < 127) {
            __syncthreads();   // each wave drains vmcnt(0): all sc1 h-stores visible
            if (tid == 0)      // relaxed slot store (sc1) — no wbl2
                __hip_atomic_store(slot_base + jb, (unsigned)(t + 1),
                                   __ATOMIC_RELAXED, __HIP_MEMORY_SCOPE_AGENT);
            // prefetch next-step proj; overlaps the next wait
            const __hip_bfloat16* pn = pbase + (size_t)(t + 1) * 32 * 1536;
            rz = pn[0]; rr_ = pn[512]; rg = pn[1024];
        }
    }
}

// ---------------- final FC ----------------
__global__ __launch_bounds__(256)
void fc_kernel(const float* __restrict__ seq, const float* __restrict__ Wfc,
               const float* __restrict__ bfc, float* __restrict__ out)
{
    int idx = blockIdx.x * 256 + threadIdx.x;   // 0..16383
    int b = idx >> 9, o = idx & 511;
    const float* catf = seq + ((size_t)(0 * 128 + 127) * 32 + b) * 512;  // fwd, t=127
    const float* catr = seq + ((size_t)(1 * 128 + 0) * 32 + b) * 512;    // rev, t=0
    float acc = bfc[o];
    #pragma unroll 8
    for (int k = 0; k < 512; k++) acc += catf[k] * Wfc[(size_t)k * 512 + o];
    #pragma unroll 8
    for (int k = 0; k < 512; k++) acc += catr[k] * Wfc[(size_t)(512 + k) * 512 + o];
    out[(size_t)b * 512 + o] = acc;
}

extern "C" void kernel_launch(void* const* d_in, const int* in_sizes, int n_in,
                              void* d_out, int out_size, void* d_ws, size_t ws_size,
                              hipStream_t stream) {
    (void)in_sizes; (void)n_in; (void)out_size; (void)ws_size;
    const float* x   = (const float*)d_in[0];
    const float* Wxh = (const float*)d_in[1];
    const float* bxh = (const float*)d_in[2];
    const float* Whh = (const float*)d_in[3];
    const float* bhh = (const float*)d_in[4];
    const float* Wxr = (const float*)d_in[5];
    const float* bxr = (const float*)d_in[6];
    const float* Whr = (const float*)d_in[7];
    const float* bhr = (const float*)d_in[8];
    const float* Wfc = (const float*)d_in[9];
    const float* bfc = (const float*)d_in[10];
    float* out = (float*)d_out;

    char* base = (char*)d_ws;
    __hip_bfloat16* proj = (__hip_bfloat16*)base;
    float* seq   = (float*)(base + (size_t)PROJ_ELEMS * 2);
    float* slabs = seq + SEQ_ELEMS;

    repack_kernel<<<512, 256, 0, stream>>>(Whh, Whr, slabs);

    dim3 pgrid(12, 64);
    proj_kernel<<<pgrid, 256, 0, stream>>>(x, Wxh, bxh, Wxr, bxr, proj, 0);
    {
        int layer = 0;
        void* args[] = {(void*)&proj, (void*)&seq, (void*)&slabs,
                        (void*)&bhh, (void*)&bhr, (void*)&layer};
        hipLaunchCooperativeKernel((void*)gru_seq_kernel, dim3(256), dim3(1024),
                                   args, 0, stream);
    }
    proj_kernel<<<pgrid, 256, 0, stream>>>(seq, Wxh, bxh, Wxr, bxr, proj, 1);
    {
        int layer = 1;
        void* args[] = {(void*)&proj, (void*)&seq, (void*)&slabs,
                        (void*)&bhh, (void*)&bhr, (void*)&layer};
        hipLaunchCooperativeKernel((void*)gru_seq_kernel, dim3(256), dim3(1024),
                                   args, 0, stream);
    }
    fc_kernel<<<64, 256, 0, stream>>>(seq, Wfc, bfc, out);
}

// Round 13
// 7975.002 us; speedup vs baseline: 1.0534x; 1.0534x over previous
//
#include <hip/hip_runtime.h>
#include <hip/hip_bf16.h>

// Problem: B=32, T=128, I=H=O=512, L=2, bidirectional GRU + FC head.
// ws layout (bytes):
//   proj (bf16): [2][128][32][1536]            = 12,582,912 elems * 2B = 25.17 MB
//   seq  (fp32): [2][128][32][512]             =  4,194,304 elems * 4B = 16.78 MB
//   slabs(fp32): [2l][2d][128jb][6144]         =  6,291,456 elems * 4B = 25.17 MB
// total 67.12 MB; sync slots live in __device__ globals (zeroed by repack each launch)
#define PROJ_ELEMS 12582912
#define SEQ_ELEMS  4194304
#define SLAB_PER_BLK 6144

typedef float f32x4 __attribute__((ext_vector_type(4)));

// Block-granular dataflow slots (R7-proven): g_slots[ld*128 + jb] = epoch published
// by block (d,jb) of layer ld: value t+1 means h(t) cols [4jb,4jb+4) are LLC-visible.
// All traffic RELAXED agent-scope (sc1) — no wbl2/inv. Monotonic, no reset.
__device__ unsigned g_slots[512];

// ---------------- proj GEMM: [8192 x 1536] = src @ [Wxh | Wxr] + bias -> bf16 ----------------
// grid (12, 64), block 256. 128x128 tile, 8x8 per-thread register tile.
__global__ __launch_bounds__(256)
void proj_kernel(const float* __restrict__ src,
                 const float* __restrict__ Wxh, const float* __restrict__ bxh,
                 const float* __restrict__ Wxr, const float* __restrict__ bxr,
                 __hip_bfloat16* __restrict__ proj, int layer)
{
    __shared__ float As[32][137];   // [k][row] transposed A tile
    __shared__ float Ws[32][132];   // [k][col]
    const int tid  = threadIdx.x;
    const int col0 = blockIdx.x * 128;
    const int row0 = blockIdx.y * 128;
    const int d    = row0 >> 12;              // rows 0..4095 = dir0, 4096..8191 = dir1
    const int ld   = layer * 2 + d;
    const int tx = tid & 15, ty = tid >> 4;

    const bool is_xr = (col0 >= 1024);
    const float* Wbase = is_xr ? (Wxr + (size_t)ld * 512 * 512 + (col0 - 1024))
                               : (Wxh + (size_t)ld * 512 * 1024 + col0);
    const int wstride = is_xr ? 512 : 1024;
    const float* bias = is_xr ? (bxr + ld * 512 + (col0 - 1024))
                              : (bxh + ld * 1024 + col0);

    float acc[8][8];
    #pragma unroll
    for (int i = 0; i < 8; i++)
        #pragma unroll
        for (int j = 0; j < 8; j++) acc[i][j] = 0.f;

    for (int k0 = 0; k0 < 512; k0 += 32) {
        #pragma unroll
        for (int v = 0; v < 4; v++) {
            int idx = tid + v * 256;
            int r   = idx >> 3;
            int c4  = (idx & 7) << 2;
            int gm  = row0 + r;
            int rr  = gm & 4095;
            int tt  = rr >> 5, bb = rr & 31;
            const float* p;
            if (layer == 0) {
                int ts = (gm >= 4096) ? (127 - tt) : tt;  // dir1 reads reversed time
                p = src + ((size_t)bb * 128 + ts) * 512 + (k0 + c4);
            } else {
                p = src + (((size_t)(gm >> 12) * 128 + tt) * 32 + bb) * 512 + (k0 + c4);
            }
            float4 vv = *(const float4*)p;
            As[c4 + 0][r] = vv.x; As[c4 + 1][r] = vv.y;
            As[c4 + 2][r] = vv.z; As[c4 + 3][r] = vv.w;
        }
        #pragma unroll
        for (int v = 0; v < 4; v++) {
            int idx = tid + v * 256;
            int kr  = idx >> 5;
            int c4  = (idx & 31) << 2;
            *(float4*)&Ws[kr][c4] = *(const float4*)(Wbase + (size_t)(k0 + kr) * wstride + c4);
        }
        __syncthreads();
        #pragma unroll
        for (int kk = 0; kk < 32; kk++) {
            float a[8], w[8];
            *(float4*)&a[0] = *(const float4*)&As[kk][ty * 8];
            *(float4*)&a[4] = *(const float4*)&As[kk][ty * 8 + 4];
            *(float4*)&w[0] = *(const float4*)&Ws[kk][tx * 8];
            *(float4*)&w[4] = *(const float4*)&Ws[kk][tx * 8 + 4];
            #pragma unroll
            for (int i = 0; i < 8; i++)
                #pragma unroll
                for (int j = 0; j < 8; j++)
                    acc[i][j] += a[i] * w[j];
        }
        __syncthreads();
    }
    #pragma unroll
    for (int i = 0; i < 8; i++) {
        int gm = row0 + ty * 8 + i;
        __hip_bfloat16* dst = proj + (size_t)gm * 1536 + col0 + tx * 8;
        #pragma unroll
        for (int j = 0; j < 8; j++)
            dst[j] = __float2bfloat16(acc[i][j] + bias[tx * 8 + j]);
    }
}

// ---------------- weight repack: per-(ld,jb) contiguous slab ----------------
// slab[(ld*128+jb)][idx], idx = (g*4+cg)*12 + e*4 + ki ; k = g*4+ki, j = jb*4+cg
// e: 0 = Whh z-col j, 1 = Whh r-col 512+j, 2 = Whr g-col j.
// Also zeroes the dataflow slots (must run before the gru kernels).
__global__ __launch_bounds__(256)
void repack_kernel(const float* __restrict__ Whh, const float* __restrict__ Whr,
                   float* __restrict__ slabs)
{
    if (blockIdx.x == 0) {
        g_slots[threadIdx.x] = 0u;
        g_slots[threadIdx.x + 256] = 0u;
    }
    const int blk = blockIdx.x;           // 0..511 = ld*128 + jb
    const int ld = blk >> 7, jb = blk & 127;
    const float* WhhL = Whh + (size_t)ld * 512 * 1024;
    const float* WhrL = Whr + (size_t)ld * 512 * 512;
    float* out = slabs + (size_t)blk * SLAB_PER_BLK;
    for (int u = 0; u < 24; u++) {
        int idx = threadIdx.x + u * 256;  // 0..6143
        int rec = idx / 12, r3 = idx % 12;
        int g = rec >> 2, cg = rec & 3;
        int e = r3 >> 2, ki = r3 & 3;
        int k = g * 4 + ki, j = jb * 4 + cg;
        float v;
        if (e == 0)      v = WhhL[(size_t)k * 1024 + j];
        else if (e == 1) v = WhhL[(size_t)k * 1024 + 512 + j];
        else             v = WhrL[(size_t)k * 512 + j];
        out[idx] = v;
    }
}

// ---------------- fused GRU sequence: all 128 timesteps, one launch ----------------
// R13 = R11 skeleton (proven, 1145us/layer) + de-spilled weight-volume cut + L2-shared
// staging. R12's lesson (measured): wzr[16] array under __launch_bounds__(1024,4)
// allocated only 64 VGPR (the 8-waves/EU cap — arg-2 semantics bit us) and spilled
// 8.5 GB/dispatch to scratch (FETCH 170MB->10.25GB). Fixes:
// (a) __launch_bounds__(1024, 1): VGPR cap >=128 under either arg-2 interpretation;
//     real occupancy stays 1 block/CU (LDS-pinned). wz as 16 NAMED f32x4 registers,
//     macro-unrolled GEMV (no runtime-indexable array -> cannot go to scratch).
//     Removes 16 of 32 per-step ds_read_b128 + their data cycles.
// (b) staging via PLAIN loads (R8-proven correct: t-indexed write-once addresses,
//     poll-ordered, dispatch boundary covers layer-1 address reuse): first block
//     per XCD fills L2 from LLC, other ~31 co-XCD blocks L2-hit (~250 vs ~700cy).
//     h STORES stay sc1 (write-through to LLC = the publish point).
// (c) wr in LDS at padded slot rec+(rec>>6): 4 addrs/bank-quad = data floor.
// Sync protocol, thread map, summation order: byte-identical to R11 -> same absmax.
#define GRU_GG(i, WZ)                                                        \
    {                                                                        \
        const int g   = kq * 16 + (i);                                       \
        const int sl  = g ^ kq;                                              \
        const int rec = g * 4 + cgi;                                         \
        float4 h4 = *(const float4*)&hw[brl * 512 + (sl << 2)];              \
        f32x4 wr4 = ((const f32x4*)wlds)[rec + kq];                          \
        f32x4 wg4 = wrec[rec * 3 + 2];                                       \
        az += h4.x * WZ.x + h4.y * WZ.y + h4.z * WZ.z + h4.w * WZ.w;         \
        ar += h4.x * wr4.x + h4.y * wr4.y + h4.z * wr4.z + h4.w * wr4.w;     \
        ag += h4.x * wg4.x + h4.y * wg4.y + h4.z * wg4.z + h4.w * wg4.w;     \
    }

__global__ __launch_bounds__(1024, 1)
void gru_seq_kernel(const __hip_bfloat16* __restrict__ proj, float* __restrict__ seq,
                    const float* __restrict__ slabs,
                    const float* __restrict__ bhh, const float* __restrict__ bhr,
                    int layer)
{
    __shared__ __align__(16) float hs[16 * 1024];  // per-wave 4KB: [w][row2][slot128*4]
    __shared__ __align__(16) float wlds[2336];     // wr only: 520 f32x4 padded slots
    const int tid  = threadIdx.x;
    const int d    = blockIdx.x >> 7;
    const int jb   = blockIdx.x & 127;
    const int ld   = layer * 2 + d;
    const int cgi  = tid & 3;
    const int kq   = (tid >> 2) & 7;
    const int b    = tid >> 5;
    const int w    = tid >> 6;
    const int lane = tid & 63;
    const int brl  = (tid >> 5) & 1;
    const int j    = jb * 4 + cgi;

    // loop invariants
    const f32x4* wrec = (const f32x4*)slabs + (size_t)(ld * 128 + jb) * 1536;
    const float bz = bhh[ld * 1024 + j];
    const float br = bhh[ld * 1024 + 512 + j];
    const float bg = bhr[ld * 512 + j];
    const float* hbase = seq + (size_t)(d * 128) * 32 * 512;
    const __hip_bfloat16* pbase = proj + ((size_t)(d * 128) * 32 + b) * 1536 + j;
    float* wout = seq + ((size_t)(d * 128) * 32 + b) * 512 + j;
    unsigned* slot_base = &g_slots[ld * 128];
    unsigned* s0p = slot_base + lane;    // each wave polls all 128 block slots
    unsigned* s1p = s0p + 64;
    float* hw = &hs[w * 1024];           // wave-private staging region (4KB)

    // one-time: wr -> LDS at padded slot i + (i>>6)  (read slot = rec + kq)
    if (tid < 512) {
        int i = tid;                     // rec 0..511
        ((f32x4*)wlds)[i + (i >> 6)] = wrec[i * 3 + 1];
    }
    // one-time: wz -> 16 NAMED registers (loop-invariant; spill-proof)
    #define WZLD(i) f32x4 wz##i = wrec[(size_t)((kq * 16 + i) * 4 + cgi) * 3]
    WZLD(0);  WZLD(1);  WZLD(2);  WZLD(3);
    WZLD(4);  WZLD(5);  WZLD(6);  WZLD(7);
    WZLD(8);  WZLD(9);  WZLD(10); WZLD(11);
    WZLD(12); WZLD(13); WZLD(14); WZLD(15);
    #undef WZLD
    __syncthreads();                     // wlds visible to all waves

    __hip_bfloat16 rz = pbase[0], rr_ = pbase[512], rg = pbase[1024];
    float hv_prev = 0.f;                 // h(t-1)[b][j] — this thread computes it

    for (int t = 0; t < 128; ++t) {
        float az = 0.f, ar = 0.f, ag = 0.f;
        if (t > 0) {
            // wait until ALL 128 producer blocks published h(t-1)  (proven R7 poll)
            const unsigned tgt = (unsigned)t;
            for (;;) {
                unsigned a = __hip_atomic_load(s0p, __ATOMIC_RELAXED,
                                               __HIP_MEMORY_SCOPE_AGENT);
                unsigned c = __hip_atomic_load(s1p, __ATOMIC_RELAXED,
                                               __HIP_MEMORY_SCOPE_AGENT);
                if (__all(a >= tgt && c >= tgt)) break;
                __builtin_amdgcn_s_sleep(1);
            }
            asm volatile("" ::: "memory");   // keep staging loads below the poll

            // stage h(t-1)[2w..2w+1][:] (4KB contiguous) into wave-private hs.
            // PLAIN loads (not sc1): producers' sc1 stores made LLC fresh; these
            // addresses were never cached pre-write, so L2 lines are fresh fills
            // shared by co-XCD blocks (R8-proven correctness, R13 latency win).
            const float* hsrc = hbase + ((size_t)(t - 1) * 32 + 2 * w) * 512;
            f32x4 tmp0 = *(const f32x4*)(hsrc + (size_t)(lane +   0) * 4);
            f32x4 tmp1 = *(const f32x4*)(hsrc + (size_t)(lane +  64) * 4);
            f32x4 tmp2 = *(const f32x4*)(hsrc + (size_t)(lane + 128) * 4);
            f32x4 tmp3 = *(const f32x4*)(hsrc + (size_t)(lane + 192) * 4);
            #define HSTORE(TMP, IDOFF)                                        \
                {                                                             \
                    int id  = lane + (IDOFF);                                 \
                    int row = id >> 7, g = id & 127;                          \
                    int sl  = g ^ ((g >> 4) & 7);                             \
                    *(f32x4*)&hw[row * 512 + (sl << 2)] = (TMP);              \
                }
            HSTORE(tmp0, 0) HSTORE(tmp1, 64) HSTORE(tmp2, 128) HSTORE(tmp3, 192)
            #undef HSTORE
            // no barrier: hw is wave-private; compiler inserts lgkmcnt for RAW

            GRU_GG(0,  wz0)  GRU_GG(1,  wz1)  GRU_GG(2,  wz2)  GRU_GG(3,  wz3)
            GRU_GG(4,  wz4)  GRU_GG(5,  wz5)  GRU_GG(6,  wz6)  GRU_GG(7,  wz7)
            GRU_GG(8,  wz8)  GRU_GG(9,  wz9)  GRU_GG(10, wz10) GRU_GG(11, wz11)
            GRU_GG(12, wz12) GRU_GG(13, wz13) GRU_GG(14, wz14) GRU_GG(15, wz15)

            // combine the 8 k-slices (kq = lane bits 2..4)
            az += __shfl_xor(az, 4, 64);  ar += __shfl_xor(ar, 4, 64);  ag += __shfl_xor(ag, 4, 64);
            az += __shfl_xor(az, 8, 64);  ar += __shfl_xor(ar, 8, 64);  ag += __shfl_xor(ag, 8, 64);
            az += __shfl_xor(az, 16, 64); ar += __shfl_xor(ar, 16, 64); ag += __shfl_xor(ag, 16, 64);
        }

        float pz = __bfloat162float(rz);
        float pr = __bfloat162float(rr_);
        float pg = __bfloat162float(rg);
        float z  = 1.f / (1.f + __expf(-(az + pz + bz)));
        float r  = 1.f / (1.f + __expf(-(ar + pr + br)));
        float gt = tanhf((ag + bg) * r + pg);
        float hn = z * hv_prev + (1.f - z) * gt;
        hv_prev = hn;                      // becomes hv_self of step t+1
        if (kq == 0)   // coherent (sc1) write-through: LLC is the merge point
            __hip_atomic_store(wout + (size_t)t * 32 * 512, hn,
                               __ATOMIC_RELAXED, __HIP_MEMORY_SCOPE_AGENT);

        // ---- single per-step barrier + block-granular publish (proven R7) ----
        if (t < 127) {
            __syncthreads();   // each wave drains vmcnt(0): all sc1 h-stores visible
            if (tid == 0)      // relaxed slot store (sc1) — no wbl2
                __hip_atomic_store(slot_base + jb, (unsigned)(t + 1),
                                   __ATOMIC_RELAXED, __HIP_MEMORY_SCOPE_AGENT);
            // prefetch next-step proj; overlaps the next wait
            const __hip_bfloat16* pn = pbase + (size_t)(t + 1) * 32 * 1536;
            rz = pn[0]; rr_ = pn[512]; rg = pn[1024];
        }
    }
}

// ---------------- final FC ----------------
__global__ __launch_bounds__(256)
void fc_kernel(const float* __restrict__ seq, const float* __restrict__ Wfc,
               const float* __restrict__ bfc, float* __restrict__ out)
{
    int idx = blockIdx.x * 256 + threadIdx.x;   // 0..16383
    int b = idx >> 9, o = idx & 511;
    const float* catf = seq + ((size_t)(0 * 128 + 127) * 32 + b) * 512;  // fwd, t=127
    const float* catr = seq + ((size_t)(1 * 128 + 0) * 32 + b) * 512;    // rev, t=0
    float acc = bfc[o];
    #pragma unroll 8
    for (int k = 0; k < 512; k++) acc += catf[k] * Wfc[(size_t)k * 512 + o];
    #pragma unroll 8
    for (int k = 0; k < 512; k++) acc += catr[k] * Wfc[(size_t)(512 + k) * 512 + o];
    out[(size_t)b * 512 + o] = acc;
}

extern "C" void kernel_launch(void* const* d_in, const int* in_sizes, int n_in,
                              void* d_out, int out_size, void* d_ws, size_t ws_size,
                              hipStream_t stream) {
    (void)in_sizes; (void)n_in; (void)out_size; (void)ws_size;
    const float* x   = (const float*)d_in[0];
    const float* Wxh = (const float*)d_in[1];
    const float* bxh = (const float*)d_in[2];
    const float* Whh = (const float*)d_in[3];
    const float* bhh = (const float*)d_in[4];
    const float* Wxr = (const float*)d_in[5];
    const float* bxr = (const float*)d_in[6];
    const float* Whr = (const float*)d_in[7];
    const float* bhr = (const float*)d_in[8];
    const float* Wfc = (const float*)d_in[9];
    const float* bfc = (const float*)d_in[10];
    float* out = (float*)d_out;

    char* base = (char*)d_ws;
    __hip_bfloat16* proj = (__hip_bfloat16*)base;
    float* seq   = (float*)(base + (size_t)PROJ_ELEMS * 2);
    float* slabs = seq + SEQ_ELEMS;

    repack_kernel<<<512, 256, 0, stream>>>(Whh, Whr, slabs);

    dim3 pgrid(12, 64);
    proj_kernel<<<pgrid, 256, 0, stream>>>(x, Wxh, bxh, Wxr, bxr, proj, 0);
    {
        int layer = 0;
        void* args[] = {(void*)&proj, (void*)&seq, (void*)&slabs,
                        (void*)&bhh, (void*)&bhr, (void*)&layer};
        hipLaunchCooperativeKernel((void*)gru_seq_kernel, dim3(256), dim3(1024),
                                   args, 0, stream);
    }
    proj_kernel<<<pgrid, 256, 0, stream>>>(seq, Wxh, bxh, Wxr, bxr, proj, 1);
    {
        int layer = 1;
        void* args[] = {(void*)&proj, (void*)&seq, (void*)&slabs,
                        (void*)&bhh, (void*)&bhr, (void*)&layer};
        hipLaunchCooperativeKernel((void*)gru_seq_kernel, dim3(256), dim3(1024),
                                   args, 0, stream);
    }
    fc_kernel<<<64, 256, 0, stream>>>(seq, Wfc, bfc, out);
}

// Round 14
// 2717.858 us; speedup vs baseline: 3.0909x; 2.9343x over previous
//
#include <hip/hip_runtime.h>
#include <hip/hip_bf16.h>

// Problem: B=32, T=128, I=H=O=512, L=2, bidirectional GRU + FC head.
// ws layout (bytes):
//   proj (bf16): [2][128][32][1536]            = 12,582,912 elems * 2B = 25.17 MB
//   seq  (fp32): [2][128][32][512]             =  4,194,304 elems * 4B = 16.78 MB
//   slabs(fp32): [2l][2d][128jb][6144]         =  6,291,456 elems * 4B = 25.17 MB
// total 67.12 MB; sync slots live in __device__ globals (zeroed by repack each launch)
#define PROJ_ELEMS 12582912
#define SEQ_ELEMS  4194304
#define SLAB_PER_BLK 6144

typedef float f32x4 __attribute__((ext_vector_type(4)));

// Block-granular dataflow slots (R7-proven): g_slots[ld*128 + jb] = epoch published
// by block (d,jb) of layer ld: value t+1 means h(t) cols [4jb,4jb+4) are LLC-visible.
// All traffic RELAXED agent-scope (sc1) — no wbl2/inv. Monotonic, no reset.
__device__ unsigned g_slots[512];

// ---------------- proj GEMM: [8192 x 1536] = src @ [Wxh | Wxr] + bias -> bf16 ----------------
// grid (12, 64), block 256. 128x128 tile, 8x8 per-thread register tile.
__global__ __launch_bounds__(256)
void proj_kernel(const float* __restrict__ src,
                 const float* __restrict__ Wxh, const float* __restrict__ bxh,
                 const float* __restrict__ Wxr, const float* __restrict__ bxr,
                 __hip_bfloat16* __restrict__ proj, int layer)
{
    __shared__ float As[32][137];   // [k][row] transposed A tile
    __shared__ float Ws[32][132];   // [k][col]
    const int tid  = threadIdx.x;
    const int col0 = blockIdx.x * 128;
    const int row0 = blockIdx.y * 128;
    const int d    = row0 >> 12;              // rows 0..4095 = dir0, 4096..8191 = dir1
    const int ld   = layer * 2 + d;
    const int tx = tid & 15, ty = tid >> 4;

    const bool is_xr = (col0 >= 1024);
    const float* Wbase = is_xr ? (Wxr + (size_t)ld * 512 * 512 + (col0 - 1024))
                               : (Wxh + (size_t)ld * 512 * 1024 + col0);
    const int wstride = is_xr ? 512 : 1024;
    const float* bias = is_xr ? (bxr + ld * 512 + (col0 - 1024))
                              : (bxh + ld * 1024 + col0);

    float acc[8][8];
    #pragma unroll
    for (int i = 0; i < 8; i++)
        #pragma unroll
        for (int j = 0; j < 8; j++) acc[i][j] = 0.f;

    for (int k0 = 0; k0 < 512; k0 += 32) {
        #pragma unroll
        for (int v = 0; v < 4; v++) {
            int idx = tid + v * 256;
            int r   = idx >> 3;
            int c4  = (idx & 7) << 2;
            int gm  = row0 + r;
            int rr  = gm & 4095;
            int tt  = rr >> 5, bb = rr & 31;
            const float* p;
            if (layer == 0) {
                int ts = (gm >= 4096) ? (127 - tt) : tt;  // dir1 reads reversed time
                p = src + ((size_t)bb * 128 + ts) * 512 + (k0 + c4);
            } else {
                p = src + (((size_t)(gm >> 12) * 128 + tt) * 32 + bb) * 512 + (k0 + c4);
            }
            float4 vv = *(const float4*)p;
            As[c4 + 0][r] = vv.x; As[c4 + 1][r] = vv.y;
            As[c4 + 2][r] = vv.z; As[c4 + 3][r] = vv.w;
        }
        #pragma unroll
        for (int v = 0; v < 4; v++) {
            int idx = tid + v * 256;
            int kr  = idx >> 5;
            int c4  = (idx & 31) << 2;
            *(float4*)&Ws[kr][c4] = *(const float4*)(Wbase + (size_t)(k0 + kr) * wstride + c4);
        }
        __syncthreads();
        #pragma unroll
        for (int kk = 0; kk < 32; kk++) {
            float a[8], w[8];
            *(float4*)&a[0] = *(const float4*)&As[kk][ty * 8];
            *(float4*)&a[4] = *(const float4*)&As[kk][ty * 8 + 4];
            *(float4*)&w[0] = *(const float4*)&Ws[kk][tx * 8];
            *(float4*)&w[4] = *(const float4*)&Ws[kk][tx * 8 + 4];
            #pragma unroll
            for (int i = 0; i < 8; i++)
                #pragma unroll
                for (int j = 0; j < 8; j++)
                    acc[i][j] += a[i] * w[j];
        }
        __syncthreads();
    }
    #pragma unroll
    for (int i = 0; i < 8; i++) {
        int gm = row0 + ty * 8 + i;
        __hip_bfloat16* dst = proj + (size_t)gm * 1536 + col0 + tx * 8;
        #pragma unroll
        for (int j = 0; j < 8; j++)
            dst[j] = __float2bfloat16(acc[i][j] + bias[tx * 8 + j]);
    }
}

// ---------------- weight repack: per-(ld,jb) contiguous slab ----------------
// slab[(ld*128+jb)][idx], idx = (g*4+cg)*12 + e*4 + ki ; k = g*4+ki, j = jb*4+cg
// e: 0 = Whh z-col j, 1 = Whh r-col 512+j, 2 = Whr g-col j.
// Also zeroes the dataflow slots (must run before the gru kernels).
__global__ __launch_bounds__(256)
void repack_kernel(const float* __restrict__ Whh, const float* __restrict__ Whr,
                   float* __restrict__ slabs)
{
    if (blockIdx.x == 0) {
        g_slots[threadIdx.x] = 0u;
        g_slots[threadIdx.x + 256] = 0u;
    }
    const int blk = blockIdx.x;           // 0..511 = ld*128 + jb
    const int ld = blk >> 7, jb = blk & 127;
    const float* WhhL = Whh + (size_t)ld * 512 * 1024;
    const float* WhrL = Whr + (size_t)ld * 512 * 512;
    float* out = slabs + (size_t)blk * SLAB_PER_BLK;
    for (int u = 0; u < 24; u++) {
        int idx = threadIdx.x + u * 256;  // 0..6143
        int rec = idx / 12, r3 = idx % 12;
        int g = rec >> 2, cg = rec & 3;
        int e = r3 >> 2, ki = r3 & 3;
        int k = g * 4 + ki, j = jb * 4 + cg;
        float v;
        if (e == 0)      v = WhhL[(size_t)k * 1024 + j];
        else if (e == 1) v = WhhL[(size_t)k * 1024 + 512 + j];
        else             v = WhrL[(size_t)k * 512 + j];
        out[idx] = v;
    }
}

// ---------------- fused GRU sequence: all 128 timesteps, one launch ----------------
// R14 = R11 verbatim (proven: no spill, VGPR 52, 1145us/layer) + two serial-chain
// cuts, each backed by passing rounds:
// (a) staging via PLAIN loads (R8/R13 both passed with them): producers' sc1
//     stores land at the LLC; staging addresses are first-touched-after-publish
//     within this dispatch (dispatch-boundary invalidate covers the layer-1 seq
//     address reuse), so plain loads can never see stale lines. First toucher per
//     XCD fills L2 (~700cy), the other ~31 co-XCD blocks L2-hit (~250cy).
// (b) single-wave poll: wave 0 polls the 128 slots alone and releases the block
//     through __syncthreads (extra barrier proven ~free by R7-vs-R11). Cuts the
//     16x-redundant LLC slot-read traffic that sat on the critical path.
// R12/R13 lesson honored: NO register-array weights (hipcc caps this kernel at
// 64 VGPR regardless of launch_bounds; demanding more = 9GB scratch spill).
// Thread map / GEMV / weight layout / summation order: R11 -> same absmax.
__global__ __launch_bounds__(1024, 4)
void gru_seq_kernel(const __hip_bfloat16* __restrict__ proj, float* __restrict__ seq,
                    const float* __restrict__ slabs,
                    const float* __restrict__ bhh, const float* __restrict__ bhr,
                    int layer)
{
    __shared__ __align__(16) float hs[16 * 1024];  // per-wave 4KB: [w][row2][slot128*4]
    __shared__ __align__(16) float wlds[4100];     // wz/wr compact, kq>=4 half +4 floats
    const int tid  = threadIdx.x;
    const int d    = blockIdx.x >> 7;
    const int jb   = blockIdx.x & 127;
    const int ld   = layer * 2 + d;
    const int cgi  = tid & 3;
    const int kq   = (tid >> 2) & 7;
    const int b    = tid >> 5;
    const int w    = tid >> 6;
    const int lane = tid & 63;
    const int brl  = (tid >> 5) & 1;
    const int j    = jb * 4 + cgi;

    // loop invariants
    const f32x4* wrec = (const f32x4*)slabs + (size_t)(ld * 128 + jb) * 1536;
    const float bz = bhh[ld * 1024 + j];
    const float br = bhh[ld * 1024 + 512 + j];
    const float bg = bhr[ld * 512 + j];
    const float* hbase = seq + (size_t)(d * 128) * 32 * 512;
    const __hip_bfloat16* pbase = proj + ((size_t)(d * 128) * 32 + b) * 1536 + j;
    float* wout = seq + ((size_t)(d * 128) * 32 + b) * 512 + j;
    unsigned* slot_base = &g_slots[ld * 128];
    unsigned* s0p = slot_base + lane;    // wave-0 poll targets (2 slots per lane)
    unsigned* s1p = s0p + 64;
    float* hw = &hs[w * 1024];           // wave-private staging region (4KB)

    // one-time: stage wz/wr into compact LDS layout (1 float4 per thread).
    // i = rec*2 + e; dest shifted +1 float4 for the g>=64 half (i>=512).
    {
        int i = tid;                     // 0..1023
        ((f32x4*)wlds)[i + (i >= 512 ? 1 : 0)] = wrec[(i >> 1) * 3 + (i & 1)];
    }
    __syncthreads();                     // wlds visible to all waves

    __hip_bfloat16 rz = pbase[0], rr_ = pbase[512], rg = pbase[1024];
    float hv_prev = 0.f;                 // h(t-1)[b][j] — this thread computes it

    for (int t = 0; t < 128; ++t) {
        float az = 0.f, ar = 0.f, ag = 0.f;
        if (t > 0) {
            // wave 0 polls all 128 producer slots; other waves sleep at the barrier
            if (tid < 64) {
                const unsigned tgt = (unsigned)t;
                for (;;) {
                    unsigned a = __hip_atomic_load(s0p, __ATOMIC_RELAXED,
                                                   __HIP_MEMORY_SCOPE_AGENT);
                    unsigned c = __hip_atomic_load(s1p, __ATOMIC_RELAXED,
                                                   __HIP_MEMORY_SCOPE_AGENT);
                    if (__all(a >= tgt && c >= tgt)) break;
                    __builtin_amdgcn_s_sleep(1);
                }
            }
            __syncthreads();                 // release: h(t-1) is LLC-visible
            asm volatile("" ::: "memory");   // keep staging loads below the poll

            // stage h(t-1)[2w..2w+1][:] (4KB contiguous) into wave-private hs.
            // PLAIN loads (R8/R13-proven): L2 lines are fresh fills shared by
            // co-XCD blocks. Swizzle slot = g ^ ((g>>4)&7) -> GEMV reads free 2-way.
            const float* hsrc = hbase + ((size_t)(t - 1) * 32 + 2 * w) * 512;
            f32x4 tmp0 = *(const f32x4*)(hsrc + (size_t)(lane +   0) * 4);
            f32x4 tmp1 = *(const f32x4*)(hsrc + (size_t)(lane +  64) * 4);
            f32x4 tmp2 = *(const f32x4*)(hsrc + (size_t)(lane + 128) * 4);
            f32x4 tmp3 = *(const f32x4*)(hsrc + (size_t)(lane + 192) * 4);
            #define HSTORE(TMP, IDOFF)                                        \
                {                                                             \
                    int id  = lane + (IDOFF);                                 \
                    int row = id >> 7, g = id & 127;                          \
                    int sl  = g ^ ((g >> 4) & 7);                             \
                    *(f32x4*)&hw[row * 512 + (sl << 2)] = (TMP);              \
                }
            HSTORE(tmp0, 0) HSTORE(tmp1, 64) HSTORE(tmp2, 128) HSTORE(tmp3, 192)
            #undef HSTORE
            // no barrier: hw is wave-private; compiler inserts lgkmcnt for RAW

            #pragma unroll
            for (int gg = 0; gg < 16; gg++) {
                int g   = kq * 16 + gg;
                int sl  = g ^ kq;                 // (g>>4)&7 == kq here
                int rec = g * 4 + cgi;
                float4 h4 = *(const float4*)&hw[brl * 512 + (sl << 2)];
                const f32x4* wp = (const f32x4*)wlds + (rec << 1) + (kq >> 2);
                f32x4 wz = wp[0], wr = wp[1];     // LDS (volume-floor reads)
                f32x4 wg = wrec[rec * 3 + 2];     // global slab, L1-resident
                az += h4.x * wz.x + h4.y * wz.y + h4.z * wz.z + h4.w * wz.w;
                ar += h4.x * wr.x + h4.y * wr.y + h4.z * wr.z + h4.w * wr.w;
                ag += h4.x * wg.x + h4.y * wg.y + h4.z * wg.z + h4.w * wg.w;
            }
            // combine the 8 k-slices (kq = lane bits 2..4)
            az += __shfl_xor(az, 4, 64);  ar += __shfl_xor(ar, 4, 64);  ag += __shfl_xor(ag, 4, 64);
            az += __shfl_xor(az, 8, 64);  ar += __shfl_xor(ar, 8, 64);  ag += __shfl_xor(ag, 8, 64);
            az += __shfl_xor(az, 16, 64); ar += __shfl_xor(ar, 16, 64); ag += __shfl_xor(ag, 16, 64);
        }

        float pz = __bfloat162float(rz);
        float pr = __bfloat162float(rr_);
        float pg = __bfloat162float(rg);
        float z  = 1.f / (1.f + __expf(-(az + pz + bz)));
        float r  = 1.f / (1.f + __expf(-(ar + pr + br)));
        float gt = tanhf((ag + bg) * r + pg);
        float hn = z * hv_prev + (1.f - z) * gt;
        hv_prev = hn;                      // becomes hv_self of step t+1
        if (kq == 0)   // coherent (sc1) write-through: LLC is the merge point
            __hip_atomic_store(wout + (size_t)t * 32 * 512, hn,
                               __ATOMIC_RELAXED, __HIP_MEMORY_SCOPE_AGENT);

        // ---- per-step barrier + block-granular publish (proven R7/R11) ----
        if (t < 127) {
            __syncthreads();   // each wave drains vmcnt(0): all sc1 h-stores visible
            if (tid == 0)      // relaxed slot store (sc1) — no wbl2
                __hip_atomic_store(slot_base + jb, (unsigned)(t + 1),
                                   __ATOMIC_RELAXED, __HIP_MEMORY_SCOPE_AGENT);
            // prefetch next-step proj; overlaps the next wait
            const __hip_bfloat16* pn = pbase + (size_t)(t + 1) * 32 * 1536;
            rz = pn[0]; rr_ = pn[512]; rg = pn[1024];
        }
    }
}

// ---------------- final FC ----------------
__global__ __launch_bounds__(256)
void fc_kernel(const float* __restrict__ seq, const float* __restrict__ Wfc,
               const float* __restrict__ bfc, float* __restrict__ out)
{
    int idx = blockIdx.x * 256 + threadIdx.x;   // 0..16383
    int b = idx >> 9, o = idx & 511;
    const float* catf = seq + ((size_t)(0 * 128 + 127) * 32 + b) * 512;  // fwd, t=127
    const float* catr = seq + ((size_t)(1 * 128 + 0) * 32 + b) * 512;    // rev, t=0
    float acc = bfc[o];
    #pragma unroll 8
    for (int k = 0; k < 512; k++) acc += catf[k] * Wfc[(size_t)k * 512 + o];
    #pragma unroll 8
    for (int k = 0; k < 512; k++) acc += catr[k] * Wfc[(size_t)(512 + k) * 512 + o];
    out[(size_t)b * 512 + o] = acc;
}

extern "C" void kernel_launch(void* const* d_in, const int* in_sizes, int n_in,
                              void* d_out, int out_size, void* d_ws, size_t ws_size,
                              hipStream_t stream) {
    (void)in_sizes; (void)n_in; (void)out_size; (void)ws_size;
    const float* x   = (const float*)d_in[0];
    const float* Wxh = (const float*)d_in[1];
    const float* bxh = (const float*)d_in[2];
    const float* Whh = (const float*)d_in[3];
    const float* bhh = (const float*)d_in[4];
    const float* Wxr = (const float*)d_in[5];
    const float* bxr = (const float*)d_in[6];
    const float* Whr = (const float*)d_in[7];
    const float* bhr = (const float*)d_in[8];
    const float* Wfc = (const float*)d_in[9];
    const float* bfc = (const float*)d_in[10];
    float* out = (float*)d_out;

    char* base = (char*)d_ws;
    __hip_bfloat16* proj = (__hip_bfloat16*)base;
    float* seq   = (float*)(base + (size_t)PROJ_ELEMS * 2);
    float* slabs = seq + SEQ_ELEMS;

    repack_kernel<<<512, 256, 0, stream>>>(Whh, Whr, slabs);

    dim3 pgrid(12, 64);
    proj_kernel<<<pgrid, 256, 0, stream>>>(x, Wxh, bxh, Wxr, bxr, proj, 0);
    {
        int layer = 0;
        void* args[] = {(void*)&proj, (void*)&seq, (void*)&slabs,
                        (void*)&bhh, (void*)&bhr, (void*)&layer};
        hipLaunchCooperativeKernel((void*)gru_seq_kernel, dim3(256), dim3(1024),
                                   args, 0, stream);
    }
    proj_kernel<<<pgrid, 256, 0, stream>>>(seq, Wxh, bxh, Wxr, bxr, proj, 1);
    {
        int layer = 1;
        void* args[] = {(void*)&proj, (void*)&seq, (void*)&slabs,
                        (void*)&bhh, (void*)&bhr, (void*)&layer};
        hipLaunchCooperativeKernel((void*)gru_seq_kernel, dim3(256), dim3(1024),
                                   args, 0, stream);
    }
    fc_kernel<<<64, 256, 0, stream>>>(seq, Wfc, bfc, out);
}

// Round 15
// 2624.662 us; speedup vs baseline: 3.2007x; 1.0355x over previous
//
#include <hip/hip_runtime.h>
#include <hip/hip_bf16.h>

// Problem: B=32, T=128, I=H=O=512, L=2, bidirectional GRU + FC head.
// ws layout (bytes):
//   proj (bf16): [2][128][32][1536]            = 12,582,912 elems * 2B = 25.17 MB
//   seq  (fp32): [2][128][32][512]             =  4,194,304 elems * 4B = 16.78 MB
//   slabs(fp32): [2l][2d][128jb][6144]         =  6,291,456 elems * 4B = 25.17 MB
// total 67.12 MB; sync slots live in __device__ globals (zeroed by repack each launch)
//
// SESSION LEDGER (dur_us total / gru us-per-layer):
//   R0 baseline 256 step-kernel launches: 2708 / ~9.4us-step
//   R1 coop grid.sync: 9673 (ockl sync ~33us/step)     R2 ctr barrier: 5748
//   R3 slot barrier: 6087    R4 sc1 fence-free: 3080 / 1325
//   R5 LDS weights: 2910 / 1250    R6 dataflow+conflict-free: 3007 / 1325
//   R7 1024thr 4-wave-TLP: 2608 / 1113  <-- BEST (this file)
//   R8 no-staging: 3103 / 1435    R10 wave-granular: 7035 / 3195
//   R11 1-barrier+reg-hself: 2673 / 1145   R12/R13 VGPR-spill: 8400/7975
//   R14 plain-loads+1wave-poll: 2717 / 1195
// Conclusion: ~8.7us/step = ~3us VALU issue + ~5.7us lockstep-exchange latency;
// five protocol redesigns (R6,R10,R11,R14 + canary analysis) tie or regress.
#define PROJ_ELEMS 12582912
#define SEQ_ELEMS  4194304
#define SLAB_PER_BLK 6144

typedef float f32x4 __attribute__((ext_vector_type(4)));

// Producer-keyed dataflow slots: g_slots[ld*128 + jb] = epoch published by block
// (d,jb) of layer ld: value t+1 means h(t) for columns [4jb,4jb+4) is LLC-visible.
// All traffic RELAXED agent-scope (sc1) — no wbl2/inv. Monotonic, no reset.
__device__ unsigned g_slots[512];

// ---------------- proj GEMM: [8192 x 1536] = src @ [Wxh | Wxr] + bias -> bf16 ----------------
// grid (12, 64), block 256. 128x128 tile, 8x8 per-thread register tile.
__global__ __launch_bounds__(256)
void proj_kernel(const float* __restrict__ src,
                 const float* __restrict__ Wxh, const float* __restrict__ bxh,
                 const float* __restrict__ Wxr, const float* __restrict__ bxr,
                 __hip_bfloat16* __restrict__ proj, int layer)
{
    __shared__ float As[32][137];   // [k][row] transposed A tile
    __shared__ float Ws[32][132];   // [k][col]
    const int tid  = threadIdx.x;
    const int col0 = blockIdx.x * 128;
    const int row0 = blockIdx.y * 128;
    const int d    = row0 >> 12;              // rows 0..4095 = dir0, 4096..8191 = dir1
    const int ld   = layer * 2 + d;
    const int tx = tid & 15, ty = tid >> 4;

    const bool is_xr = (col0 >= 1024);
    const float* Wbase = is_xr ? (Wxr + (size_t)ld * 512 * 512 + (col0 - 1024))
                               : (Wxh + (size_t)ld * 512 * 1024 + col0);
    const int wstride = is_xr ? 512 : 1024;
    const float* bias = is_xr ? (bxr + ld * 512 + (col0 - 1024))
                              : (bxh + ld * 1024 + col0);

    float acc[8][8];
    #pragma unroll
    for (int i = 0; i < 8; i++)
        #pragma unroll
        for (int j = 0; j < 8; j++) acc[i][j] = 0.f;

    for (int k0 = 0; k0 < 512; k0 += 32) {
        #pragma unroll
        for (int v = 0; v < 4; v++) {
            int idx = tid + v * 256;
            int r   = idx >> 3;
            int c4  = (idx & 7) << 2;
            int gm  = row0 + r;
            int rr  = gm & 4095;
            int tt  = rr >> 5, bb = rr & 31;
            const float* p;
            if (layer == 0) {
                int ts = (gm >= 4096) ? (127 - tt) : tt;  // dir1 reads reversed time
                p = src + ((size_t)bb * 128 + ts) * 512 + (k0 + c4);
            } else {
                p = src + (((size_t)(gm >> 12) * 128 + tt) * 32 + bb) * 512 + (k0 + c4);
            }
            float4 vv = *(const float4*)p;
            As[c4 + 0][r] = vv.x; As[c4 + 1][r] = vv.y;
            As[c4 + 2][r] = vv.z; As[c4 + 3][r] = vv.w;
        }
        #pragma unroll
        for (int v = 0; v < 4; v++) {
            int idx = tid + v * 256;
            int kr  = idx >> 5;
            int c4  = (idx & 31) << 2;
            *(float4*)&Ws[kr][c4] = *(const float4*)(Wbase + (size_t)(k0 + kr) * wstride + c4);
        }
        __syncthreads();
        #pragma unroll
        for (int kk = 0; kk < 32; kk++) {
            float a[8], w[8];
            *(float4*)&a[0] = *(const float4*)&As[kk][ty * 8];
            *(float4*)&a[4] = *(const float4*)&As[kk][ty * 8 + 4];
            *(float4*)&w[0] = *(const float4*)&Ws[kk][tx * 8];
            *(float4*)&w[4] = *(const float4*)&Ws[kk][tx * 8 + 4];
            #pragma unroll
            for (int i = 0; i < 8; i++)
                #pragma unroll
                for (int j = 0; j < 8; j++)
                    acc[i][j] += a[i] * w[j];
        }
        __syncthreads();
    }
    #pragma unroll
    for (int i = 0; i < 8; i++) {
        int gm = row0 + ty * 8 + i;
        __hip_bfloat16* dst = proj + (size_t)gm * 1536 + col0 + tx * 8;
        #pragma unroll
        for (int j = 0; j < 8; j++)
            dst[j] = __float2bfloat16(acc[i][j] + bias[tx * 8 + j]);
    }
}

// ---------------- weight repack: per-(ld,jb) contiguous slab ----------------
// slab[(ld*128+jb)][idx], idx = (g*4+cg)*12 + e*4 + ki ; k = g*4+ki, j = jb*4+cg
// e: 0 = Whh z-col j, 1 = Whh r-col 512+j, 2 = Whr g-col j.
// Also zeroes the dataflow slots (must run before the gru kernels).
__global__ __launch_bounds__(256)
void repack_kernel(const float* __restrict__ Whh, const float* __restrict__ Whr,
                   float* __restrict__ slabs)
{
    if (blockIdx.x == 0) {
        g_slots[threadIdx.x] = 0u;
        g_slots[threadIdx.x + 256] = 0u;
    }
    const int blk = blockIdx.x;           // 0..511 = ld*128 + jb
    const int ld = blk >> 7, jb = blk & 127;
    const float* WhhL = Whh + (size_t)ld * 512 * 1024;
    const float* WhrL = Whr + (size_t)ld * 512 * 512;
    float* out = slabs + (size_t)blk * SLAB_PER_BLK;
    for (int u = 0; u < 24; u++) {
        int idx = threadIdx.x + u * 256;  // 0..6143
        int rec = idx / 12, r3 = idx % 12;
        int g = rec >> 2, cg = rec & 3;
        int e = r3 >> 2, ki = r3 & 3;
        int k = g * 4 + ki, j = jb * 4 + cg;
        float v;
        if (e == 0)      v = WhhL[(size_t)k * 1024 + j];
        else if (e == 1) v = WhhL[(size_t)k * 1024 + 512 + j];
        else             v = WhrL[(size_t)k * 512 + j];
        out[idx] = v;
    }
}

// ---------------- fused GRU sequence: all 128 timesteps, one launch ----------------
// R7 configuration (session best, 2608us total). 1024-thread blocks: thread =
// (cgi=tid&3, kq=(tid>>2)&7, b=tid>>5), 16 gg iters, shfl_xor(4/8/16) k-combine.
// 16 waves/block = 4 waves/SIMD hides DS/L1/LLC latency (the R7 lever: Occupancy
// 12%->48%). hs swizzle slot(b,g) = g ^ (b&7) ^ ((g>>4)&7) spreads a wave's 8
// kq-reads over 8 bank quads. Weights: wz/wr compact in LDS (kq-half +16B), wg
// streams from the L1-resident global slab (TA pipe parallel to DS pipe).
// Sync: block-granular sc1 slots — sc1 h-stores -> __syncthreads vmcnt drain ->
// sc1 publish -> consumer poll -> control-dependent sc1 staging loads.
// Measured-and-rejected variants: R11's 1-barrier/reg-hself (tie), R14's plain
// loads + 1-wave poll (worse), R10 wave-granular (2.9x worse), R12/R13
// register-array weights (hipcc caps this kernel at 64 VGPR -> 9GB scratch spill).
__global__ __launch_bounds__(1024, 4)
void gru_seq_kernel(const __hip_bfloat16* __restrict__ proj, float* __restrict__ seq,
                    const float* __restrict__ slabs,
                    const float* __restrict__ bhh, const float* __restrict__ bhr,
                    int layer)
{
    __shared__ __align__(16) float hs[32 * 512];   // h: [b][slot(b,g)*4 + ki]
    __shared__ __align__(16) float wlds[4100];     // wz/wr compact, kq>=4 half +4 floats
    const int tid = threadIdx.x;
    const int d   = blockIdx.x >> 7;
    const int jb  = blockIdx.x & 127;
    const int ld  = layer * 2 + d;
    const int cgi = tid & 3;
    const int kq  = (tid >> 2) & 7;
    const int b   = tid >> 5;
    const int j   = jb * 4 + cgi;
    const int sb  = b & 7;

    // loop invariants, loaded once per layer
    const f32x4* wrec = (const f32x4*)slabs + (size_t)(ld * 128 + jb) * 1536;
    const float bz = bhh[ld * 1024 + j];
    const float br = bhh[ld * 1024 + 512 + j];
    const float bg = bhr[ld * 512 + j];
    const float* hbase = seq + (size_t)(d * 128) * 32 * 512;
    const __hip_bfloat16* pbase = proj + ((size_t)(d * 128) * 32 + b) * 1536 + j;
    float* wout = seq + ((size_t)(d * 128) * 32 + b) * 512 + j;
    unsigned* slot_base = &g_slots[ld * 128];
    unsigned* myslot = slot_base + (tid & 127);   // this thread's staging producer

    // one-time: stage wz/wr into compact LDS layout (1 float4 per thread).
    // i = rec*2 + e; dest shifted +1 float4 for the g>=64 half (i>=512).
    {
        int i = tid;                         // 0..1023
        ((f32x4*)wlds)[i + (i >= 512 ? 1 : 0)] = wrec[(i >> 1) * 3 + (i & 1)];
    }

    // software-pipelined proj load for t=0 (read-only data, normal cached loads)
    __hip_bfloat16 rz = pbase[0], rr_ = pbase[512], rg = pbase[1024];

    for (int t = 0; t < 128; ++t) {
        if (t > 0) {
            // wait for THIS thread's producer (wave-granular __all over 64 slots;
            // even waves poll jb 0..63, odd waves 64..127), then stage h(t-1).
            const unsigned tgt = (unsigned)t;
            for (;;) {
                unsigned s = __hip_atomic_load(myslot, __ATOMIC_RELAXED,
                                               __HIP_MEMORY_SCOPE_AGENT);
                if (__all(s >= tgt)) break;
                __builtin_amdgcn_s_sleep(1);
            }
            const float* hsrc = hbase + (size_t)(t - 1) * 32 * 512;
            f32x4 tmp[4];
            #pragma unroll
            for (int v = 0; v < 4; v++) {
                int id = tid + v * 1024;          // float4 id 0..4095
                asm volatile("global_load_dwordx4 %0, %1, off sc0 sc1"
                             : "=v"(tmp[v])
                             : "v"((const void*)(hsrc + (size_t)id * 4)));
            }
            asm volatile("s_waitcnt vmcnt(0)" ::: "memory");
            #pragma unroll
            for (int v = 0; v < 4; v++) {
                int id = tid + v * 1024;
                int bb = id >> 7, g = id & 127;
                int sl = g ^ (bb & 7) ^ ((g >> 4) & 7);
                *(f32x4*)&hs[bb * 512 + (sl << 2)] = tmp[v];
            }
        }
        __syncthreads();   // full h tile staged (and wlds visible at t=0)

        float pz = __bfloat162float(rz);
        float pr = __bfloat162float(rr_);
        float pg = __bfloat162float(rg);

        float az = 0.f, ar = 0.f, ag = 0.f;
        float hv_self = 0.f;
        if (t > 0) {
            #pragma unroll 4
            for (int gg = 0; gg < 16; gg++) {
                int g  = kq * 16 + gg;
                int sl = g ^ sb ^ kq;             // (g>>4)&7 == kq for this thread
                int rec = g * 4 + cgi;
                float4 h4 = *(const float4*)&hs[b * 512 + (sl << 2)];
                const f32x4* wp = (const f32x4*)wlds + (rec << 1) + (kq >> 2);
                f32x4 wz = wp[0], wr = wp[1];     // LDS, 4/quad on all 8 quads
                f32x4 wg = wrec[rec * 3 + 2];     // global slab, L1-resident
                az += h4.x * wz.x + h4.y * wz.y + h4.z * wz.z + h4.w * wz.w;
                ar += h4.x * wr.x + h4.y * wr.y + h4.z * wr.z + h4.w * wr.w;
                ag += h4.x * wg.x + h4.y * wg.y + h4.z * wg.z + h4.w * wg.w;
            }
            // combine the 8 k-slices (kq = lane bits 2..4)
            az += __shfl_xor(az, 4, 64);  ar += __shfl_xor(ar, 4, 64);  ag += __shfl_xor(ag, 4, 64);
            az += __shfl_xor(az, 8, 64);  ar += __shfl_xor(ar, 8, 64);  ag += __shfl_xor(ag, 8, 64);
            az += __shfl_xor(az, 16, 64); ar += __shfl_xor(ar, 16, 64); ag += __shfl_xor(ag, 16, 64);
            hv_self = hs[b * 512 + ((jb ^ sb ^ (jb >> 4)) << 2) + cgi];  // g_self = jb
        }

        float z  = 1.f / (1.f + __expf(-(az + pz + bz)));
        float r  = 1.f / (1.f + __expf(-(ar + pr + br)));
        float gt = tanhf((ag + bg) * r + pg);
        float hn = z * hv_self + (1.f - z) * gt;
        if (kq == 0)   // coherent (sc1) write-through so other XCDs' sc1 loads see it
            __hip_atomic_store(wout + (size_t)t * 32 * 512, hn,
                               __ATOMIC_RELAXED, __HIP_MEMORY_SCOPE_AGENT);

        // ---- publish h(t): visible to every consumer of columns [4jb,4jb+4) ----
        if (t < 127) {
            __syncthreads();   // each wave drains vmcnt(0): all sc1 h-stores visible
            if (tid == 0)      // relaxed slot store (sc1) — no wbl2
                __hip_atomic_store(slot_base + jb, (unsigned)(t + 1),
                                   __ATOMIC_RELAXED, __HIP_MEMORY_SCOPE_AGENT);
            // prefetch next-step proj; overlaps the next wait (registers survive)
            const __hip_bfloat16* pn = pbase + (size_t)(t + 1) * 32 * 1536;
            rz = pn[0]; rr_ = pn[512]; rg = pn[1024];
        }
    }
}

// ---------------- final FC ----------------
__global__ __launch_bounds__(256)
void fc_kernel(const float* __restrict__ seq, const float* __restrict__ Wfc,
               const float* __restrict__ bfc, float* __restrict__ out)
{
    int idx = blockIdx.x * 256 + threadIdx.x;   // 0..16383
    int b = idx >> 9, o = idx & 511;
    const float* catf = seq + ((size_t)(0 * 128 + 127) * 32 + b) * 512;  // fwd, t=127
    const float* catr = seq + ((size_t)(1 * 128 + 0) * 32 + b) * 512;    // rev, t=0
    float acc = bfc[o];
    #pragma unroll 8
    for (int k = 0; k < 512; k++) acc += catf[k] * Wfc[(size_t)k * 512 + o];
    #pragma unroll 8
    for (int k = 0; k < 512; k++) acc += catr[k] * Wfc[(size_t)(512 + k) * 512 + o];
    out[(size_t)b * 512 + o] = acc;
}

extern "C" void kernel_launch(void* const* d_in, const int* in_sizes, int n_in,
                              void* d_out, int out_size, void* d_ws, size_t ws_size,
                              hipStream_t stream) {
    (void)in_sizes; (void)n_in; (void)out_size; (void)ws_size;
    const float* x   = (const float*)d_in[0];
    const float* Wxh = (const float*)d_in[1];
    const float* bxh = (const float*)d_in[2];
    const float* Whh = (const float*)d_in[3];
    const float* bhh = (const float*)d_in[4];
    const float* Wxr = (const float*)d_in[5];
    const float* bxr = (const float*)d_in[6];
    const float* Whr = (const float*)d_in[7];
    const float* bhr = (const float*)d_in[8];
    const float* Wfc = (const float*)d_in[9];
    const float* bfc = (const float*)d_in[10];
    float* out = (float*)d_out;

    char* base = (char*)d_ws;
    __hip_bfloat16* proj = (__hip_bfloat16*)base;
    float* seq   = (float*)(base + (size_t)PROJ_ELEMS * 2);
    float* slabs = seq + SEQ_ELEMS;

    repack_kernel<<<512, 256, 0, stream>>>(Whh, Whr, slabs);

    dim3 pgrid(12, 64);
    proj_kernel<<<pgrid, 256, 0, stream>>>(x, Wxh, bxh, Wxr, bxr, proj, 0);
    {
        int layer = 0;
        void* args[] = {(void*)&proj, (void*)&seq, (void*)&slabs,
                        (void*)&bhh, (void*)&bhr, (void*)&layer};
        hipLaunchCooperativeKernel((void*)gru_seq_kernel, dim3(256), dim3(1024),
                                   args, 0, stream);
    }
    proj_kernel<<<pgrid, 256, 0, stream>>>(seq, Wxh, bxh, Wxr, bxr, proj, 1);
    {
        int layer = 1;
        void* args[] = {(void*)&proj, (void*)&seq, (void*)&slabs,
                        (void*)&bhh, (void*)&bhr, (void*)&layer};
        hipLaunchCooperativeKernel((void*)gru_seq_kernel, dim3(256), dim3(1024),
                                   args, 0, stream);
    }
    fc_kernel<<<64, 256, 0, stream>>>(seq, Wfc, bfc, out);
}